// Round 12
// baseline (592.089 us; speedup 1.0000x reference)
//
#include <hip/hip_runtime.h>

// VectorQuantizer: z [16,1024,512] f32, emb [8192,512] f32
// out: [z_q_st (16384*512 f32)][total_loss (1 f32)][idx as f32 (16384)]
//
// fp8-e4m3 MFMA computes approx dot(z, emb*4096) (argmax acc == argmin dist);
// epilogue keeps per-(row,256-tile) max + extras within MARGIN_A of the tile max;
// finalize rechecks candidates with the EXACT fp32 d-ascending fmaf chain +
// q = fl(s1-2*dot) quantization (bit-identical to the round-2 kernel that passed
// absmax 0), lowest-index ties. Tiles within global margin whose extras
// overflowed the 7-slot cap get a FULL 256-code exact scan (correctness is
// independent of candidate-count statistics).

#define N_TOK 16384
#define DIM   512
#define NEMB  8192
#define BETA  0.25f
#define NKT   32
#define MARGIN_A 3.2f        // scaled units (acc = 4096*dot); 9.8 sigma_pair recall
#define ESCALE 4096.0f

using f32x4 = __attribute__((ext_vector_type(4))) float;

// ---- ws layout (bytes), total ~33.7 MB ----
#define WS_CNT  0
#define WS_PMAX (N_TOK*NKT*4)
#define WS_PIDX (WS_PMAX + N_TOK*NKT*4)
#define WS_EXTK (WS_PIDX + N_TOK*NKT*4)
#define WS_S1   (WS_EXTK + N_TOK*NKT*7*4)
#define WS_PART (WS_S1   + N_TOK*4)
#define WS_ZH   (WS_PART + (N_TOK/4)*8)
#define WS_EH   (WS_ZH   + N_TOK*DIM)

#define GLDS16(g, l) __builtin_amdgcn_global_load_lds( \
    (const __attribute__((address_space(1))) void*)(g), \
    (__attribute__((address_space(3))) void*)(l), 16, 0, 0)

// RNE float -> OCP e4m3fn byte (|f| < 448 assumed; handles subnormals).
__device__ inline unsigned f2e4m3(float f) {
  unsigned u = __builtin_bit_cast(unsigned, f);
  unsigned s = (u >> 24) & 0x80u;
  float a = __builtin_bit_cast(float, u & 0x7fffffffu);
  if (a < 0.015625f) {                         // e4m3 subnormal, unit 2^-9
    unsigned q = (unsigned)rintf(a * 512.0f);  // 0..8 (8 encodes 2^-6 normal)
    return s | q;
  }
  unsigned m = u & 0x7fffffffu;
  m += 0x7ffffu + ((m >> 20) & 1u);            // RNE to 3-bit mantissa
  unsigned e = (m >> 23) - 127u + 7u;
  return s | (e << 3) | ((m >> 20) & 7u);
}

__device__ inline unsigned pack4(float a, float b, float c, float d) {
  return f2e4m3(a) | (f2e4m3(b) << 8) | (f2e4m3(c) << 16) | (f2e4m3(d) << 24);
}

// Fused pack: blocks [0, N_TOK/4) pack z (scale 1) + s1; rest pack emb (scale 4096).
__global__ void vq_pack(const float* __restrict__ z, const float* __restrict__ emb,
                        unsigned char* __restrict__ zh8, unsigned char* __restrict__ eh8,
                        float* __restrict__ s1) {
  const int w = threadIdx.x >> 6, lane = threadIdx.x & 63;
  if (blockIdx.x < N_TOK / 4) {
    const int row = blockIdx.x * 4 + w;
    const float4* r = (const float4*)(z + (size_t)row * DIM);
    float4 v0 = r[lane * 2], v1 = r[lane * 2 + 1];
    // s1: bit-identical to the passing round-2 path
    float p0=v0.x*v0.x, p1=v0.y*v0.y, p2=v0.z*v0.z, p3=v0.w*v0.w;
    float p4=v1.x*v1.x, p5=v1.y*v1.y, p6=v1.z*v1.z, p7=v1.w*v1.w;
    double s = (double)p0+(double)p1+(double)p2+(double)p3
             + (double)p4+(double)p5+(double)p6+(double)p7;
    #pragma unroll
    for (int m = 32; m >= 1; m >>= 1) s += __shfl_xor(s, m);
    if (lane == 0) s1[row] = (float)s;
    uint2 o;
    o.x = pack4(v0.x, v0.y, v0.z, v0.w);
    o.y = pack4(v1.x, v1.y, v1.z, v1.w);
    const int mt = row >> 6, mi = row & 63;        // kc == lane
    *(uint2*)(zh8 + ((((size_t)mt * 64 + lane) * 64) + mi) * 8) = o;
  } else {
    const int row = (blockIdx.x - N_TOK / 4) * 4 + w;
    const float4* r = (const float4*)(emb + (size_t)row * DIM);
    float4 v0 = r[lane * 2], v1 = r[lane * 2 + 1];
    uint2 o;
    o.x = pack4(v0.x*ESCALE, v0.y*ESCALE, v0.z*ESCALE, v0.w*ESCALE);
    o.y = pack4(v1.x*ESCALE, v1.y*ESCALE, v1.z*ESCALE, v1.w*ESCALE);
    const int nt = row >> 8, ni = row & 255;
    *(uint2*)(eh8 + ((((size_t)nt * 64 + lane) * 256) + ni) * 8) = o;
  }
}

// fp8 MFMA GEMM + fused argmax/candidate epilogue.
// Block = 64 rows x 256 cols, 4 waves (1m x 4n), wave tile 64x64, BK=128,
// single-buffered 40KB LDS; R10's winning TLP schedule (4 steps x 10 loads/thr).
__global__ __launch_bounds__(256, 4)
void vq_mfma(const unsigned char* __restrict__ zh8, const unsigned char* __restrict__ eh8,
             float* __restrict__ pmax, int* __restrict__ pidx,
             int* __restrict__ cnt, int* __restrict__ extk) {
  __shared__ uint2 lA[16 * 64];    // [kc16][mi(64)]  : 8KB
  __shared__ uint2 lB[16 * 256];   // [kc16][ni(256)] : 32KB

  const int mt = blockIdx.x, nt = blockIdx.y;
  const int n0 = nt * 256, m0 = mt * 64;
  const int tid = threadIdx.x;
  const int wid = tid >> 6, lane = tid & 63;        // wid == wn (1m x 4n)
  const int quad = lane >> 4, lc = lane & 15;

  f32x4 C[4][4];
  #pragma unroll
  for (int i = 0; i < 4; ++i)
    #pragma unroll
    for (int j = 0; j < 4; ++j) C[i][j] = (f32x4){0.f, 0.f, 0.f, 0.f};

  const char* gA = (const char*)zh8 + (size_t)mt * 32768;   // 64kc*64mi*8B panel
  const char* gB = (const char*)eh8 + (size_t)nt * 131072;  // 64kc*256ni*8B panel

  for (int t = 0; t < 4; ++t) {                // K-tile of 128 (16 kc-chunks)
    {
      const char* a = gA + (size_t)t * 8192;
      const char* b = gB + (size_t)t * 32768;
      GLDS16(a + tid * 16,        (char*)&lA[0] + tid * 16);
      GLDS16(a + 4096 + tid * 16, (char*)&lA[0] + 4096 + tid * 16);
      #pragma unroll
      for (int i = 0; i < 8; ++i)
        GLDS16(b + i * 4096 + tid * 16, (char*)&lB[0] + i * 4096 + tid * 16);
    }
    __syncthreads();
    #pragma unroll
    for (int s = 0; s < 4; ++s) {              // four K=32 slots per BK=128 tile
      const int kx = s * 4 + quad;
      long long a0 = __builtin_bit_cast(long long, lA[kx * 64 +  0 + lc]);
      long long a1 = __builtin_bit_cast(long long, lA[kx * 64 + 16 + lc]);
      long long a2 = __builtin_bit_cast(long long, lA[kx * 64 + 32 + lc]);
      long long a3 = __builtin_bit_cast(long long, lA[kx * 64 + 48 + lc]);
      long long b0 = __builtin_bit_cast(long long, lB[kx * 256 + wid * 64 +  0 + lc]);
      long long b1 = __builtin_bit_cast(long long, lB[kx * 256 + wid * 64 + 16 + lc]);
      long long b2 = __builtin_bit_cast(long long, lB[kx * 256 + wid * 64 + 32 + lc]);
      long long b3 = __builtin_bit_cast(long long, lB[kx * 256 + wid * 64 + 48 + lc]);
      C[0][0] = __builtin_amdgcn_mfma_f32_16x16x32_fp8_fp8(a0, b0, C[0][0], 0, 0, 0);
      C[0][1] = __builtin_amdgcn_mfma_f32_16x16x32_fp8_fp8(a0, b1, C[0][1], 0, 0, 0);
      C[0][2] = __builtin_amdgcn_mfma_f32_16x16x32_fp8_fp8(a0, b2, C[0][2], 0, 0, 0);
      C[0][3] = __builtin_amdgcn_mfma_f32_16x16x32_fp8_fp8(a0, b3, C[0][3], 0, 0, 0);
      C[1][0] = __builtin_amdgcn_mfma_f32_16x16x32_fp8_fp8(a1, b0, C[1][0], 0, 0, 0);
      C[1][1] = __builtin_amdgcn_mfma_f32_16x16x32_fp8_fp8(a1, b1, C[1][1], 0, 0, 0);
      C[1][2] = __builtin_amdgcn_mfma_f32_16x16x32_fp8_fp8(a1, b2, C[1][2], 0, 0, 0);
      C[1][3] = __builtin_amdgcn_mfma_f32_16x16x32_fp8_fp8(a1, b3, C[1][3], 0, 0, 0);
      C[2][0] = __builtin_amdgcn_mfma_f32_16x16x32_fp8_fp8(a2, b0, C[2][0], 0, 0, 0);
      C[2][1] = __builtin_amdgcn_mfma_f32_16x16x32_fp8_fp8(a2, b1, C[2][1], 0, 0, 0);
      C[2][2] = __builtin_amdgcn_mfma_f32_16x16x32_fp8_fp8(a2, b2, C[2][2], 0, 0, 0);
      C[2][3] = __builtin_amdgcn_mfma_f32_16x16x32_fp8_fp8(a2, b3, C[2][3], 0, 0, 0);
      C[3][0] = __builtin_amdgcn_mfma_f32_16x16x32_fp8_fp8(a3, b0, C[3][0], 0, 0, 0);
      C[3][1] = __builtin_amdgcn_mfma_f32_16x16x32_fp8_fp8(a3, b1, C[3][1], 0, 0, 0);
      C[3][2] = __builtin_amdgcn_mfma_f32_16x16x32_fp8_fp8(a3, b2, C[3][2], 0, 0, 0);
      C[3][3] = __builtin_amdgcn_mfma_f32_16x16x32_fp8_fp8(a3, b3, C[3][3], 0, 0, 0);
    }
    __syncthreads();
  }

  // ---- epilogue (aliases lA/lB; C layout dtype-independent) ----
  float* cmbv = (float*)&lA[0];               // [64][4]
  int*   cmbk = (int*)(cmbv + 256);
  float* bbv  = (float*)(cmbk + 256);
  int*   bbk  = (int*)(bbv + 64);
  int*   lcnt = (int*)(bbk + 64);             // [64]

  #pragma unroll
  for (int mf = 0; mf < 4; ++mf)
    #pragma unroll
    for (int rr = 0; rr < 4; ++rr) {
      float bv = C[mf][0][rr]; int bn = 0;
      #pragma unroll
      for (int nf = 1; nf < 4; ++nf) {
        float v = C[mf][nf][rr];
        if (v > bv) { bv = v; bn = nf; }      // strict >: ties -> lowest nf (lowest k)
      }
      int bk = n0 + wid * 64 + bn * 16 + lc;
      #pragma unroll
      for (int m = 8; m >= 1; m >>= 1) {      // reduce 16 lanes (same quad)
        float vo = __shfl_xor(bv, m); int ko = __shfl_xor(bk, m);
        if (vo > bv || (vo == bv && ko < bk)) { bv = vo; bk = ko; }
      }
      if (lc == 0) {
        int row = mf * 16 + quad * 4 + rr;
        cmbv[row * 4 + wid] = bv; cmbk[row * 4 + wid] = bk;
      }
    }
  __syncthreads();
  if (tid < 64) {
    float bv = cmbv[tid * 4 + 0]; int bk = cmbk[tid * 4 + 0];
    #pragma unroll
    for (int q = 1; q < 4; ++q) {             // ascending wid => ascending k: strict >
      float v = cmbv[tid * 4 + q]; int k = cmbk[tid * 4 + q];
      if (v > bv) { bv = v; bk = k; }
    }
    bbv[tid] = bv; bbk[tid] = bk;
    lcnt[tid] = 0;
    size_t rg = (size_t)(m0 + tid) * NKT + nt;
    pmax[rg] = bv; pidx[rg] = bk;
  }
  __syncthreads();
  // emit near-max extras (cnt records TRUE count; >7 signals finalize full-scan)
  #pragma unroll
  for (int mf = 0; mf < 4; ++mf)
    #pragma unroll
    for (int nf = 0; nf < 4; ++nf)
      #pragma unroll
      for (int rr = 0; rr < 4; ++rr) {
        int row = mf * 16 + quad * 4 + rr;
        float v = C[mf][nf][rr];
        if (v >= bbv[row] - MARGIN_A) {
          int k = n0 + wid * 64 + nf * 16 + lc;
          if (k != bbk[row]) {
            int slot = atomicAdd(&lcnt[row], 1);
            if (slot < 7) extk[((size_t)(m0 + row) * NKT + nt) * 7 + slot] = k;
          }
        }
      }
  __syncthreads();
  if (tid < 64) cnt[(size_t)(m0 + tid) * NKT + nt] = lcnt[tid];
}

// EXACT fp32 q(k): strict d-ascending fmaf chain + single-rounding quantize.
// Bit-identical to the round-2 proven chain (same order); dbuf-pipelined loads.
__device__ inline float exact_q(const float4* z4, const float* __restrict__ emb,
                                int k, float s1) {
  const float4* e4 = (const float4*)(emb + (size_t)k * DIM);
  float4 zb[2][4], eb[2][4];
  #pragma unroll
  for (int j = 0; j < 4; ++j) { zb[0][j] = z4[j]; eb[0][j] = e4[j]; }
  float d = 0.f;
  #pragma unroll
  for (int c2 = 0; c2 < 32; ++c2) {
    const int cur = c2 & 1;
    if (c2 < 31) {
      #pragma unroll
      for (int j = 0; j < 4; ++j) {
        zb[cur ^ 1][j] = z4[(c2 + 1) * 4 + j];
        eb[cur ^ 1][j] = e4[(c2 + 1) * 4 + j];
      }
    }
    #pragma unroll
    for (int j = 0; j < 4; ++j) {
      float4 zv = zb[cur][j], ev = eb[cur][j];
      d = fmaf(zv.x, ev.x, d); d = fmaf(zv.y, ev.y, d);
      d = fmaf(zv.z, ev.z, d); d = fmaf(zv.w, ev.w, d);
    }
  }
  return s1 - 2.f * d;                        // 2*d exact; single rounding
}

// per-row: candidate gather (fixed 8-slot regions, no race drops) + overflow
// full-scan fallback; exact recheck; gather/outputs; per-block loss partial.
__global__ void vq_finalize(const float* __restrict__ z, const float* __restrict__ emb,
                            const float* __restrict__ s1g,
                            const float* __restrict__ pmax, const int* __restrict__ pidx,
                            const int* __restrict__ cnt, const int* __restrict__ extk,
                            float* __restrict__ out, double* __restrict__ part) {
  __shared__ int candk[4][256];
  __shared__ unsigned char cw[4][32];
  __shared__ double lossp[4];
  const int w = threadIdx.x >> 6, l = threadIdx.x & 63;
  const int row = blockIdx.x * 4 + w;
  const int l5 = l & 31;
  const size_t rb = (size_t)row * NKT;

  float pv = pmax[rb + l5]; int pk = pidx[rb + l5];
  float gv = pv; int gk = pk;
  #pragma unroll
  for (int m = 16; m >= 1; m >>= 1) {
    float vo = __shfl_xor(gv, m); int ko = __shfl_xor(gk, m);
    if (vo > gv || (vo == gv && ko < gk)) { gv = vo; gk = ko; }
  }
  const bool inm = (l < 32) && (pv >= gv - MARGIN_A);
  int c = 0; bool ovf = false;
  if (inm) { c = cnt[rb + l5]; ovf = (c > 7); }
  if (l < 32) {
    unsigned char cc = 0;
    if (inm && !ovf) {
      candk[w][l5 * 8] = pk;
      for (int i = 0; i < c; ++i) candk[w][l5 * 8 + 1 + i] = extk[(rb + l5) * 7 + i];
      cc = (unsigned char)(1 + c);
    }
    cw[w][l5] = cc;
  }
  unsigned int mask32 = (unsigned int)__ballot(ovf);   // bits 0..31 = per-tile ovf

  float qb = 1e30f; int kb = 0x7fffffff;
  const float s1 = s1g[row];
  const float* zr = z + (size_t)row * DIM;
  const float4* z4 = (const float4*)zr;
  // candidate slots (wave-coherent LDS, no barrier needed within a wave)
  for (int ci = l; ci < 256; ci += 64) {
    if ((ci & 7) < cw[w][ci >> 3]) {
      int k = candk[w][ci];
      float q = exact_q(z4, emb, k, s1);
      if (q < qb || (q == qb && k < kb)) { qb = q; kb = k; }
    }
  }
  // full-scan fallback for overflowed in-margin tiles (rare)
  while (mask32) {
    int tile = __builtin_ctz(mask32); mask32 &= mask32 - 1;
    int kbase = tile * 256 + l * 4;
    #pragma unroll
    for (int j = 0; j < 4; ++j) {
      int k = kbase + j;
      float q = exact_q(z4, emb, k, s1);
      if (q < qb || (q == qb && k < kb)) { qb = q; kb = k; }
    }
  }
  #pragma unroll
  for (int m = 32; m >= 1; m >>= 1) {
    float qo = __shfl_xor(qb, m); int ko = __shfl_xor(kb, m);
    if (qo < qb || (qo == qb && ko < kb)) { qb = qo; kb = ko; }
  }

  const float4* qr4 = (const float4*)(emb + (size_t)kb * DIM);
  float4 zv0 = z4[l * 2], zv1 = z4[l * 2 + 1];
  float4 qv0 = qr4[l * 2], qv1 = qr4[l * 2 + 1];
  float ls = 0.f; float4 ov0, ov1;
  {
    const float* zp=(const float*)&zv0; const float* qp=(const float*)&qv0; float* op=(float*)&ov0;
    #pragma unroll
    for (int e = 0; e < 4; ++e) { float d2 = qp[e]-zp[e]; op[e] = zp[e]+d2; ls += d2*d2; }
  }
  {
    const float* zp=(const float*)&zv1; const float* qp=(const float*)&qv1; float* op=(float*)&ov1;
    #pragma unroll
    for (int e = 0; e < 4; ++e) { float d2 = qp[e]-zp[e]; op[e] = zp[e]+d2; ls += d2*d2; }
  }
  float4* orow = (float4*)(out + (size_t)row * DIM);
  orow[l * 2] = ov0; orow[l * 2 + 1] = ov1;
  #pragma unroll
  for (int m = 32; m >= 1; m >>= 1) ls += __shfl_xor(ls, m);
  if (l == 0) {
    out[(size_t)N_TOK * DIM + 1 + row] = (float)kb;
    lossp[w] = (double)ls;
  }
  __syncthreads();
  if (threadIdx.x == 0)
    part[blockIdx.x] = lossp[0] + lossp[1] + lossp[2] + lossp[3];
}

// reduce 4096 per-block partials -> loss scalar
__global__ void vq_loss(const double* __restrict__ part, float* __restrict__ out) {
  __shared__ double ws[4];
  const int t = threadIdx.x, w = t >> 6, lane = t & 63;
  double s = 0.0;
  #pragma unroll
  for (int i = 0; i < 16; ++i) s += part[t + i * 256];
  #pragma unroll
  for (int m = 32; m >= 1; m >>= 1) s += __shfl_xor(s, m);
  if (lane == 0) ws[w] = s;
  __syncthreads();
  if (t == 0) {
    double tot = ws[0] + ws[1] + ws[2] + ws[3];
    out[(size_t)N_TOK * DIM] =
        (float)(tot * (1.0 + (double)BETA) / ((double)N_TOK * (double)DIM));
  }
}

extern "C" void kernel_launch(void* const* d_in, const int* in_sizes, int n_in,
                              void* d_out, int out_size, void* d_ws, size_t ws_size,
                              hipStream_t stream) {
  const float* z   = (const float*)d_in[0];
  const float* emb = (const float*)d_in[1];
  float* out = (float*)d_out;
  char* ws = (char*)d_ws;
  int*           cnt  = (int*)(ws + WS_CNT);
  float*         pmax = (float*)(ws + WS_PMAX);
  int*           pidx = (int*)(ws + WS_PIDX);
  int*           extk = (int*)(ws + WS_EXTK);
  float*         s1   = (float*)(ws + WS_S1);
  double*        part = (double*)(ws + WS_PART);
  unsigned char* zh8  = (unsigned char*)(ws + WS_ZH);
  unsigned char* eh8  = (unsigned char*)(ws + WS_EH);

  vq_pack<<<N_TOK / 4 + NEMB / 4, 256, 0, stream>>>(z, emb, zh8, eh8, s1);
  vq_mfma<<<dim3(N_TOK / 64, NEMB / 256), 256, 0, stream>>>(zh8, eh8, pmax, pidx, cnt, extk);
  vq_finalize<<<N_TOK / 4, 256, 0, stream>>>(z, emb, s1, pmax, pidx, cnt, extk, out, part);
  vq_loss<<<1, 256, 0, stream>>>(part, out);
}

// Round 13
// 573.491 us; speedup vs baseline: 1.0324x; 1.0324x over previous
//
#include <hip/hip_runtime.h>

// VectorQuantizer: z [16,1024,512] f32, emb [8192,512] f32
// out: [z_q_st (16384*512 f32)][total_loss (1 f32)][idx as f32 (16384)]
//
// fp8-e4m3 MFMA computes approx dot(z, emb*4096) (argmax acc == argmin dist);
// epilogue keeps per-(row,256-tile) max + extras within MARGIN_A of the tile max;
// finalize rechecks candidates with the EXACT fp32 d-ascending fmaf chain +
// q = fl(s1-2*dot) quantization (bit-identical to the round-2 kernel that passed
// absmax 0), lowest-index ties. Overflowed in-margin tiles -> full 256-code exact
// scan (correctness independent of candidate statistics).
//
// Round 13: fix rule-#20 scratch spill in exact_q (R12's float4[2][4] dbuf buffers
// went to scratch: VGPR=64, WRITE 108MB, 400us). Revert to the R2-R10 proven
// scalar fmaf chain (same bit-exact order, broadcast z reads, no buffers).

#define N_TOK 16384
#define DIM   512
#define NEMB  8192
#define BETA  0.25f
#define NKT   32
#define MARGIN_A 3.2f        // scaled units (acc = 4096*dot); 9.8 sigma_pair recall
#define ESCALE 4096.0f

using f32x4 = __attribute__((ext_vector_type(4))) float;

// ---- ws layout (bytes), total ~33.7 MB ----
#define WS_CNT  0
#define WS_PMAX (N_TOK*NKT*4)
#define WS_PIDX (WS_PMAX + N_TOK*NKT*4)
#define WS_EXTK (WS_PIDX + N_TOK*NKT*4)
#define WS_S1   (WS_EXTK + N_TOK*NKT*7*4)
#define WS_PART (WS_S1   + N_TOK*4)
#define WS_ZH   (WS_PART + (N_TOK/4)*8)
#define WS_EH   (WS_ZH   + N_TOK*DIM)

#define GLDS16(g, l) __builtin_amdgcn_global_load_lds( \
    (const __attribute__((address_space(1))) void*)(g), \
    (__attribute__((address_space(3))) void*)(l), 16, 0, 0)

// RNE float -> OCP e4m3fn byte (|f| < 448 assumed; handles subnormals).
__device__ inline unsigned f2e4m3(float f) {
  unsigned u = __builtin_bit_cast(unsigned, f);
  unsigned s = (u >> 24) & 0x80u;
  float a = __builtin_bit_cast(float, u & 0x7fffffffu);
  if (a < 0.015625f) {                         // e4m3 subnormal, unit 2^-9
    unsigned q = (unsigned)rintf(a * 512.0f);  // 0..8 (8 encodes 2^-6 normal)
    return s | q;
  }
  unsigned m = u & 0x7fffffffu;
  m += 0x7ffffu + ((m >> 20) & 1u);            // RNE to 3-bit mantissa
  unsigned e = (m >> 23) - 127u + 7u;
  return s | (e << 3) | ((m >> 20) & 7u);
}

__device__ inline unsigned pack4(float a, float b, float c, float d) {
  return f2e4m3(a) | (f2e4m3(b) << 8) | (f2e4m3(c) << 16) | (f2e4m3(d) << 24);
}

// Fused pack: blocks [0, N_TOK/4) pack z (scale 1) + s1; rest pack emb (scale 4096).
__global__ void vq_pack(const float* __restrict__ z, const float* __restrict__ emb,
                        unsigned char* __restrict__ zh8, unsigned char* __restrict__ eh8,
                        float* __restrict__ s1) {
  const int w = threadIdx.x >> 6, lane = threadIdx.x & 63;
  if (blockIdx.x < N_TOK / 4) {
    const int row = blockIdx.x * 4 + w;
    const float4* r = (const float4*)(z + (size_t)row * DIM);
    float4 v0 = r[lane * 2], v1 = r[lane * 2 + 1];
    // s1: bit-identical to the passing round-2 path
    float p0=v0.x*v0.x, p1=v0.y*v0.y, p2=v0.z*v0.z, p3=v0.w*v0.w;
    float p4=v1.x*v1.x, p5=v1.y*v1.y, p6=v1.z*v1.z, p7=v1.w*v1.w;
    double s = (double)p0+(double)p1+(double)p2+(double)p3
             + (double)p4+(double)p5+(double)p6+(double)p7;
    #pragma unroll
    for (int m = 32; m >= 1; m >>= 1) s += __shfl_xor(s, m);
    if (lane == 0) s1[row] = (float)s;
    uint2 o;
    o.x = pack4(v0.x, v0.y, v0.z, v0.w);
    o.y = pack4(v1.x, v1.y, v1.z, v1.w);
    const int mt = row >> 6, mi = row & 63;        // kc == lane
    *(uint2*)(zh8 + ((((size_t)mt * 64 + lane) * 64) + mi) * 8) = o;
  } else {
    const int row = (blockIdx.x - N_TOK / 4) * 4 + w;
    const float4* r = (const float4*)(emb + (size_t)row * DIM);
    float4 v0 = r[lane * 2], v1 = r[lane * 2 + 1];
    uint2 o;
    o.x = pack4(v0.x*ESCALE, v0.y*ESCALE, v0.z*ESCALE, v0.w*ESCALE);
    o.y = pack4(v1.x*ESCALE, v1.y*ESCALE, v1.z*ESCALE, v1.w*ESCALE);
    const int nt = row >> 8, ni = row & 255;
    *(uint2*)(eh8 + ((((size_t)nt * 64 + lane) * 256) + ni) * 8) = o;
  }
}

// fp8 MFMA GEMM + fused argmax/candidate epilogue.
// Block = 64 rows x 256 cols, 4 waves (1m x 4n), wave tile 64x64, BK=128,
// single-buffered 40KB LDS; R10's winning TLP schedule (4 steps x 10 loads/thr).
__global__ __launch_bounds__(256, 4)
void vq_mfma(const unsigned char* __restrict__ zh8, const unsigned char* __restrict__ eh8,
             float* __restrict__ pmax, int* __restrict__ pidx,
             int* __restrict__ cnt, int* __restrict__ extk) {
  __shared__ uint2 lA[16 * 64];    // [kc16][mi(64)]  : 8KB
  __shared__ uint2 lB[16 * 256];   // [kc16][ni(256)] : 32KB

  const int mt = blockIdx.x, nt = blockIdx.y;
  const int n0 = nt * 256, m0 = mt * 64;
  const int tid = threadIdx.x;
  const int wid = tid >> 6, lane = tid & 63;        // wid == wn (1m x 4n)
  const int quad = lane >> 4, lc = lane & 15;

  f32x4 C[4][4];
  #pragma unroll
  for (int i = 0; i < 4; ++i)
    #pragma unroll
    for (int j = 0; j < 4; ++j) C[i][j] = (f32x4){0.f, 0.f, 0.f, 0.f};

  const char* gA = (const char*)zh8 + (size_t)mt * 32768;   // 64kc*64mi*8B panel
  const char* gB = (const char*)eh8 + (size_t)nt * 131072;  // 64kc*256ni*8B panel

  for (int t = 0; t < 4; ++t) {                // K-tile of 128 (16 kc-chunks)
    {
      const char* a = gA + (size_t)t * 8192;
      const char* b = gB + (size_t)t * 32768;
      GLDS16(a + tid * 16,        (char*)&lA[0] + tid * 16);
      GLDS16(a + 4096 + tid * 16, (char*)&lA[0] + 4096 + tid * 16);
      #pragma unroll
      for (int i = 0; i < 8; ++i)
        GLDS16(b + i * 4096 + tid * 16, (char*)&lB[0] + i * 4096 + tid * 16);
    }
    __syncthreads();
    #pragma unroll
    for (int s = 0; s < 4; ++s) {              // four K=32 slots per BK=128 tile
      const int kx = s * 4 + quad;
      long long a0 = __builtin_bit_cast(long long, lA[kx * 64 +  0 + lc]);
      long long a1 = __builtin_bit_cast(long long, lA[kx * 64 + 16 + lc]);
      long long a2 = __builtin_bit_cast(long long, lA[kx * 64 + 32 + lc]);
      long long a3 = __builtin_bit_cast(long long, lA[kx * 64 + 48 + lc]);
      long long b0 = __builtin_bit_cast(long long, lB[kx * 256 + wid * 64 +  0 + lc]);
      long long b1 = __builtin_bit_cast(long long, lB[kx * 256 + wid * 64 + 16 + lc]);
      long long b2 = __builtin_bit_cast(long long, lB[kx * 256 + wid * 64 + 32 + lc]);
      long long b3 = __builtin_bit_cast(long long, lB[kx * 256 + wid * 64 + 48 + lc]);
      C[0][0] = __builtin_amdgcn_mfma_f32_16x16x32_fp8_fp8(a0, b0, C[0][0], 0, 0, 0);
      C[0][1] = __builtin_amdgcn_mfma_f32_16x16x32_fp8_fp8(a0, b1, C[0][1], 0, 0, 0);
      C[0][2] = __builtin_amdgcn_mfma_f32_16x16x32_fp8_fp8(a0, b2, C[0][2], 0, 0, 0);
      C[0][3] = __builtin_amdgcn_mfma_f32_16x16x32_fp8_fp8(a0, b3, C[0][3], 0, 0, 0);
      C[1][0] = __builtin_amdgcn_mfma_f32_16x16x32_fp8_fp8(a1, b0, C[1][0], 0, 0, 0);
      C[1][1] = __builtin_amdgcn_mfma_f32_16x16x32_fp8_fp8(a1, b1, C[1][1], 0, 0, 0);
      C[1][2] = __builtin_amdgcn_mfma_f32_16x16x32_fp8_fp8(a1, b2, C[1][2], 0, 0, 0);
      C[1][3] = __builtin_amdgcn_mfma_f32_16x16x32_fp8_fp8(a1, b3, C[1][3], 0, 0, 0);
      C[2][0] = __builtin_amdgcn_mfma_f32_16x16x32_fp8_fp8(a2, b0, C[2][0], 0, 0, 0);
      C[2][1] = __builtin_amdgcn_mfma_f32_16x16x32_fp8_fp8(a2, b1, C[2][1], 0, 0, 0);
      C[2][2] = __builtin_amdgcn_mfma_f32_16x16x32_fp8_fp8(a2, b2, C[2][2], 0, 0, 0);
      C[2][3] = __builtin_amdgcn_mfma_f32_16x16x32_fp8_fp8(a2, b3, C[2][3], 0, 0, 0);
      C[3][0] = __builtin_amdgcn_mfma_f32_16x16x32_fp8_fp8(a3, b0, C[3][0], 0, 0, 0);
      C[3][1] = __builtin_amdgcn_mfma_f32_16x16x32_fp8_fp8(a3, b1, C[3][1], 0, 0, 0);
      C[3][2] = __builtin_amdgcn_mfma_f32_16x16x32_fp8_fp8(a3, b2, C[3][2], 0, 0, 0);
      C[3][3] = __builtin_amdgcn_mfma_f32_16x16x32_fp8_fp8(a3, b3, C[3][3], 0, 0, 0);
    }
    __syncthreads();
  }

  // ---- epilogue (aliases lA/lB; C layout dtype-independent) ----
  float* cmbv = (float*)&lA[0];               // [64][4]
  int*   cmbk = (int*)(cmbv + 256);
  float* bbv  = (float*)(cmbk + 256);
  int*   bbk  = (int*)(bbv + 64);
  int*   lcnt = (int*)(bbk + 64);             // [64]

  #pragma unroll
  for (int mf = 0; mf < 4; ++mf)
    #pragma unroll
    for (int rr = 0; rr < 4; ++rr) {
      float bv = C[mf][0][rr]; int bn = 0;
      #pragma unroll
      for (int nf = 1; nf < 4; ++nf) {
        float v = C[mf][nf][rr];
        if (v > bv) { bv = v; bn = nf; }      // strict >: ties -> lowest nf (lowest k)
      }
      int bk = n0 + wid * 64 + bn * 16 + lc;
      #pragma unroll
      for (int m = 8; m >= 1; m >>= 1) {      // reduce 16 lanes (same quad)
        float vo = __shfl_xor(bv, m); int ko = __shfl_xor(bk, m);
        if (vo > bv || (vo == bv && ko < bk)) { bv = vo; bk = ko; }
      }
      if (lc == 0) {
        int row = mf * 16 + quad * 4 + rr;
        cmbv[row * 4 + wid] = bv; cmbk[row * 4 + wid] = bk;
      }
    }
  __syncthreads();
  if (tid < 64) {
    float bv = cmbv[tid * 4 + 0]; int bk = cmbk[tid * 4 + 0];
    #pragma unroll
    for (int q = 1; q < 4; ++q) {             // ascending wid => ascending k: strict >
      float v = cmbv[tid * 4 + q]; int k = cmbk[tid * 4 + q];
      if (v > bv) { bv = v; bk = k; }
    }
    bbv[tid] = bv; bbk[tid] = bk;
    lcnt[tid] = 0;
    size_t rg = (size_t)(m0 + tid) * NKT + nt;
    pmax[rg] = bv; pidx[rg] = bk;
  }
  __syncthreads();
  // emit near-max extras (cnt records TRUE count; >7 signals finalize full-scan)
  #pragma unroll
  for (int mf = 0; mf < 4; ++mf)
    #pragma unroll
    for (int nf = 0; nf < 4; ++nf)
      #pragma unroll
      for (int rr = 0; rr < 4; ++rr) {
        int row = mf * 16 + quad * 4 + rr;
        float v = C[mf][nf][rr];
        if (v >= bbv[row] - MARGIN_A) {
          int k = n0 + wid * 64 + nf * 16 + lc;
          if (k != bbk[row]) {
            int slot = atomicAdd(&lcnt[row], 1);
            if (slot < 7) extk[((size_t)(m0 + row) * NKT + nt) * 7 + slot] = k;
          }
        }
      }
  __syncthreads();
  if (tid < 64) cnt[(size_t)(m0 + tid) * NKT + nt] = lcnt[tid];
}

// EXACT fp32 q(k): strict d-ascending scalar fmaf chain + single-rounding
// quantize. Identical op order to the round-2 kernel that passed absmax 0.
// No register buffers (rule #20: avoid scratch).
__device__ inline float exact_q(const float* __restrict__ zr,
                                const float* __restrict__ emb, int k, float s1) {
  const float* er = emb + (size_t)k * DIM;
  float d = 0.f;
  for (int i = 0; i < DIM; ++i) d = fmaf(zr[i], er[i], d);
  return s1 - 2.f * d;                        // 2*d exact; single rounding
}

// per-row: candidate gather (fixed 8-slot regions, no race drops) + overflow
// full-scan fallback; exact recheck; gather/outputs; per-block loss partial.
__global__ void vq_finalize(const float* __restrict__ z, const float* __restrict__ emb,
                            const float* __restrict__ s1g,
                            const float* __restrict__ pmax, const int* __restrict__ pidx,
                            const int* __restrict__ cnt, const int* __restrict__ extk,
                            float* __restrict__ out, double* __restrict__ part) {
  __shared__ int candk[4][256];
  __shared__ unsigned char cw[4][32];
  __shared__ double lossp[4];
  const int w = threadIdx.x >> 6, l = threadIdx.x & 63;
  const int row = blockIdx.x * 4 + w;
  const int l5 = l & 31;
  const size_t rb = (size_t)row * NKT;

  float pv = pmax[rb + l5]; int pk = pidx[rb + l5];
  float gv = pv; int gk = pk;
  #pragma unroll
  for (int m = 16; m >= 1; m >>= 1) {
    float vo = __shfl_xor(gv, m); int ko = __shfl_xor(gk, m);
    if (vo > gv || (vo == gv && ko < gk)) { gv = vo; gk = ko; }
  }
  const bool inm = (l < 32) && (pv >= gv - MARGIN_A);
  int c = 0; bool ovf = false;
  if (inm) { c = cnt[rb + l5]; ovf = (c > 7); }
  if (l < 32) {
    unsigned char cc = 0;
    if (inm && !ovf) {
      candk[w][l5 * 8] = pk;
      for (int i = 0; i < c; ++i) candk[w][l5 * 8 + 1 + i] = extk[(rb + l5) * 7 + i];
      cc = (unsigned char)(1 + c);
    }
    cw[w][l5] = cc;
  }
  unsigned int mask32 = (unsigned int)__ballot(ovf);   // bits 0..31 = per-tile ovf

  float qb = 1e30f; int kb = 0x7fffffff;
  const float s1 = s1g[row];
  const float* zr = z + (size_t)row * DIM;
  // candidate slots (wave-coherent LDS)
  for (int ci = l; ci < 256; ci += 64) {
    if ((ci & 7) < cw[w][ci >> 3]) {
      int k = candk[w][ci];
      float q = exact_q(zr, emb, k, s1);
      if (q < qb || (q == qb && k < kb)) { qb = q; kb = k; }
    }
  }
  // full-scan fallback for overflowed in-margin tiles (rare)
  while (mask32) {
    int tile = __builtin_ctz(mask32); mask32 &= mask32 - 1;
    int kbase = tile * 256 + l * 4;
    #pragma unroll
    for (int j = 0; j < 4; ++j) {
      int k = kbase + j;
      float q = exact_q(zr, emb, k, s1);
      if (q < qb || (q == qb && k < kb)) { qb = q; kb = k; }
    }
  }
  #pragma unroll
  for (int m = 32; m >= 1; m >>= 1) {
    float qo = __shfl_xor(qb, m); int ko = __shfl_xor(kb, m);
    if (qo < qb || (qo == qb && ko < kb)) { qb = qo; kb = ko; }
  }

  const float4* z4 = (const float4*)zr;
  const float4* qr4 = (const float4*)(emb + (size_t)kb * DIM);
  float4 zv0 = z4[l * 2], zv1 = z4[l * 2 + 1];
  float4 qv0 = qr4[l * 2], qv1 = qr4[l * 2 + 1];
  float ls = 0.f; float4 ov0, ov1;
  {
    const float* zp=(const float*)&zv0; const float* qp=(const float*)&qv0; float* op=(float*)&ov0;
    #pragma unroll
    for (int e = 0; e < 4; ++e) { float d2 = qp[e]-zp[e]; op[e] = zp[e]+d2; ls += d2*d2; }
  }
  {
    const float* zp=(const float*)&zv1; const float* qp=(const float*)&qv1; float* op=(float*)&ov1;
    #pragma unroll
    for (int e = 0; e < 4; ++e) { float d2 = qp[e]-zp[e]; op[e] = zp[e]+d2; ls += d2*d2; }
  }
  float4* orow = (float4*)(out + (size_t)row * DIM);
  orow[l * 2] = ov0; orow[l * 2 + 1] = ov1;
  #pragma unroll
  for (int m = 32; m >= 1; m >>= 1) ls += __shfl_xor(ls, m);
  if (l == 0) {
    out[(size_t)N_TOK * DIM + 1 + row] = (float)kb;
    lossp[w] = (double)ls;
  }
  __syncthreads();
  if (threadIdx.x == 0)
    part[blockIdx.x] = lossp[0] + lossp[1] + lossp[2] + lossp[3];
}

// reduce 4096 per-block partials -> loss scalar
__global__ void vq_loss(const double* __restrict__ part, float* __restrict__ out) {
  __shared__ double ws[4];
  const int t = threadIdx.x, w = t >> 6, lane = t & 63;
  double s = 0.0;
  #pragma unroll
  for (int i = 0; i < 16; ++i) s += part[t + i * 256];
  #pragma unroll
  for (int m = 32; m >= 1; m >>= 1) s += __shfl_xor(s, m);
  if (lane == 0) ws[w] = s;
  __syncthreads();
  if (t == 0) {
    double tot = ws[0] + ws[1] + ws[2] + ws[3];
    out[(size_t)N_TOK * DIM] =
        (float)(tot * (1.0 + (double)BETA) / ((double)N_TOK * (double)DIM));
  }
}

extern "C" void kernel_launch(void* const* d_in, const int* in_sizes, int n_in,
                              void* d_out, int out_size, void* d_ws, size_t ws_size,
                              hipStream_t stream) {
  const float* z   = (const float*)d_in[0];
  const float* emb = (const float*)d_in[1];
  float* out = (float*)d_out;
  char* ws = (char*)d_ws;
  int*           cnt  = (int*)(ws + WS_CNT);
  float*         pmax = (float*)(ws + WS_PMAX);
  int*           pidx = (int*)(ws + WS_PIDX);
  int*           extk = (int*)(ws + WS_EXTK);
  float*         s1   = (float*)(ws + WS_S1);
  double*        part = (double*)(ws + WS_PART);
  unsigned char* zh8  = (unsigned char*)(ws + WS_ZH);
  unsigned char* eh8  = (unsigned char*)(ws + WS_EH);

  vq_pack<<<N_TOK / 4 + NEMB / 4, 256, 0, stream>>>(z, emb, zh8, eh8, s1);
  vq_mfma<<<dim3(N_TOK / 64, NEMB / 256), 256, 0, stream>>>(zh8, eh8, pmax, pidx, cnt, extk);
  vq_finalize<<<N_TOK / 4, 256, 0, stream>>>(z, emb, s1, pmax, pidx, cnt, extk, out, part);
  vq_loss<<<1, 256, 0, stream>>>(part, out);
}

// Round 14
// 427.408 us; speedup vs baseline: 1.3853x; 1.3418x over previous
//
#include <hip/hip_runtime.h>

// VectorQuantizer: z [16,1024,512] f32, emb [8192,512] f32
// out: [z_q_st (16384*512 f32)][total_loss (1 f32)][idx as f32 (16384)]
//
// fp8-e4m3 MFMA computes approx dot(z, emb*4096) (argmax acc == argmin dist);
// epilogue keeps per-(row,256-tile) max + extras within MARGIN_A of the tile max;
// finalize rechecks candidates with the EXACT fp32 d-ascending fmaf chain +
// q = fl(s1-2*dot) quantization (bit-identical to the round-2 kernel that passed
// absmax 0), lowest-index ties. Overflowed in-margin tiles -> full 256-code exact
// scan (correctness independent of candidate statistics).
//
// Round 14: finalize was latency-bound on uncoalesced per-lane emb rows (FETCH
// 140MB @ 457GB/s, VALUBusy 12%). Fix: block-cooperative LDS staging of candidate
// rows (coalesced wave-per-row), chains read LDS with the SAME bit-exact order.
// Stage overflow / full-scan tiles keep the global-chain fallback (rare).

#define N_TOK 16384
#define DIM   512
#define NEMB  8192
#define BETA  0.25f
#define NKT   32
#define MARGIN_A 3.2f        // scaled units (acc = 4096*dot); 9.8 sigma_pair recall
#define ESCALE 4096.0f
#define NSTAGE 24            // staged candidate rows per finalize block

using f32x4 = __attribute__((ext_vector_type(4))) float;

// ---- ws layout (bytes), total ~33.7 MB ----
#define WS_CNT  0
#define WS_PMAX (N_TOK*NKT*4)
#define WS_PIDX (WS_PMAX + N_TOK*NKT*4)
#define WS_EXTK (WS_PIDX + N_TOK*NKT*4)
#define WS_S1   (WS_EXTK + N_TOK*NKT*7*4)
#define WS_PART (WS_S1   + N_TOK*4)
#define WS_ZH   (WS_PART + (N_TOK/4)*8)
#define WS_EH   (WS_ZH   + N_TOK*DIM)

#define GLDS16(g, l) __builtin_amdgcn_global_load_lds( \
    (const __attribute__((address_space(1))) void*)(g), \
    (__attribute__((address_space(3))) void*)(l), 16, 0, 0)

// RNE float -> OCP e4m3fn byte (|f| < 448 assumed; handles subnormals).
__device__ inline unsigned f2e4m3(float f) {
  unsigned u = __builtin_bit_cast(unsigned, f);
  unsigned s = (u >> 24) & 0x80u;
  float a = __builtin_bit_cast(float, u & 0x7fffffffu);
  if (a < 0.015625f) {                         // e4m3 subnormal, unit 2^-9
    unsigned q = (unsigned)rintf(a * 512.0f);  // 0..8 (8 encodes 2^-6 normal)
    return s | q;
  }
  unsigned m = u & 0x7fffffffu;
  m += 0x7ffffu + ((m >> 20) & 1u);            // RNE to 3-bit mantissa
  unsigned e = (m >> 23) - 127u + 7u;
  return s | (e << 3) | ((m >> 20) & 7u);
}

__device__ inline unsigned pack4(float a, float b, float c, float d) {
  return f2e4m3(a) | (f2e4m3(b) << 8) | (f2e4m3(c) << 16) | (f2e4m3(d) << 24);
}

// Fused pack: blocks [0, N_TOK/4) pack z (scale 1) + s1; rest pack emb (scale 4096).
__global__ void vq_pack(const float* __restrict__ z, const float* __restrict__ emb,
                        unsigned char* __restrict__ zh8, unsigned char* __restrict__ eh8,
                        float* __restrict__ s1) {
  const int w = threadIdx.x >> 6, lane = threadIdx.x & 63;
  if (blockIdx.x < N_TOK / 4) {
    const int row = blockIdx.x * 4 + w;
    const float4* r = (const float4*)(z + (size_t)row * DIM);
    float4 v0 = r[lane * 2], v1 = r[lane * 2 + 1];
    // s1: bit-identical to the passing round-2 path
    float p0=v0.x*v0.x, p1=v0.y*v0.y, p2=v0.z*v0.z, p3=v0.w*v0.w;
    float p4=v1.x*v1.x, p5=v1.y*v1.y, p6=v1.z*v1.z, p7=v1.w*v1.w;
    double s = (double)p0+(double)p1+(double)p2+(double)p3
             + (double)p4+(double)p5+(double)p6+(double)p7;
    #pragma unroll
    for (int m = 32; m >= 1; m >>= 1) s += __shfl_xor(s, m);
    if (lane == 0) s1[row] = (float)s;
    uint2 o;
    o.x = pack4(v0.x, v0.y, v0.z, v0.w);
    o.y = pack4(v1.x, v1.y, v1.z, v1.w);
    const int mt = row >> 6, mi = row & 63;        // kc == lane
    *(uint2*)(zh8 + ((((size_t)mt * 64 + lane) * 64) + mi) * 8) = o;
  } else {
    const int row = (blockIdx.x - N_TOK / 4) * 4 + w;
    const float4* r = (const float4*)(emb + (size_t)row * DIM);
    float4 v0 = r[lane * 2], v1 = r[lane * 2 + 1];
    uint2 o;
    o.x = pack4(v0.x*ESCALE, v0.y*ESCALE, v0.z*ESCALE, v0.w*ESCALE);
    o.y = pack4(v1.x*ESCALE, v1.y*ESCALE, v1.z*ESCALE, v1.w*ESCALE);
    const int nt = row >> 8, ni = row & 255;
    *(uint2*)(eh8 + ((((size_t)nt * 64 + lane) * 256) + ni) * 8) = o;
  }
}

// fp8 MFMA GEMM + fused argmax/candidate epilogue.
// Block = 64 rows x 256 cols, 4 waves (1m x 4n), wave tile 64x64, BK=128,
// single-buffered 40KB LDS; R10's winning TLP schedule (4 steps x 10 loads/thr).
__global__ __launch_bounds__(256, 4)
void vq_mfma(const unsigned char* __restrict__ zh8, const unsigned char* __restrict__ eh8,
             float* __restrict__ pmax, int* __restrict__ pidx,
             int* __restrict__ cnt, int* __restrict__ extk) {
  __shared__ uint2 lA[16 * 64];    // [kc16][mi(64)]  : 8KB
  __shared__ uint2 lB[16 * 256];   // [kc16][ni(256)] : 32KB

  const int mt = blockIdx.x, nt = blockIdx.y;
  const int n0 = nt * 256, m0 = mt * 64;
  const int tid = threadIdx.x;
  const int wid = tid >> 6, lane = tid & 63;        // wid == wn (1m x 4n)
  const int quad = lane >> 4, lc = lane & 15;

  f32x4 C[4][4];
  #pragma unroll
  for (int i = 0; i < 4; ++i)
    #pragma unroll
    for (int j = 0; j < 4; ++j) C[i][j] = (f32x4){0.f, 0.f, 0.f, 0.f};

  const char* gA = (const char*)zh8 + (size_t)mt * 32768;   // 64kc*64mi*8B panel
  const char* gB = (const char*)eh8 + (size_t)nt * 131072;  // 64kc*256ni*8B panel

  for (int t = 0; t < 4; ++t) {                // K-tile of 128 (16 kc-chunks)
    {
      const char* a = gA + (size_t)t * 8192;
      const char* b = gB + (size_t)t * 32768;
      GLDS16(a + tid * 16,        (char*)&lA[0] + tid * 16);
      GLDS16(a + 4096 + tid * 16, (char*)&lA[0] + 4096 + tid * 16);
      #pragma unroll
      for (int i = 0; i < 8; ++i)
        GLDS16(b + i * 4096 + tid * 16, (char*)&lB[0] + i * 4096 + tid * 16);
    }
    __syncthreads();
    #pragma unroll
    for (int s = 0; s < 4; ++s) {              // four K=32 slots per BK=128 tile
      const int kx = s * 4 + quad;
      long long a0 = __builtin_bit_cast(long long, lA[kx * 64 +  0 + lc]);
      long long a1 = __builtin_bit_cast(long long, lA[kx * 64 + 16 + lc]);
      long long a2 = __builtin_bit_cast(long long, lA[kx * 64 + 32 + lc]);
      long long a3 = __builtin_bit_cast(long long, lA[kx * 64 + 48 + lc]);
      long long b0 = __builtin_bit_cast(long long, lB[kx * 256 + wid * 64 +  0 + lc]);
      long long b1 = __builtin_bit_cast(long long, lB[kx * 256 + wid * 64 + 16 + lc]);
      long long b2 = __builtin_bit_cast(long long, lB[kx * 256 + wid * 64 + 32 + lc]);
      long long b3 = __builtin_bit_cast(long long, lB[kx * 256 + wid * 64 + 48 + lc]);
      C[0][0] = __builtin_amdgcn_mfma_f32_16x16x32_fp8_fp8(a0, b0, C[0][0], 0, 0, 0);
      C[0][1] = __builtin_amdgcn_mfma_f32_16x16x32_fp8_fp8(a0, b1, C[0][1], 0, 0, 0);
      C[0][2] = __builtin_amdgcn_mfma_f32_16x16x32_fp8_fp8(a0, b2, C[0][2], 0, 0, 0);
      C[0][3] = __builtin_amdgcn_mfma_f32_16x16x32_fp8_fp8(a0, b3, C[0][3], 0, 0, 0);
      C[1][0] = __builtin_amdgcn_mfma_f32_16x16x32_fp8_fp8(a1, b0, C[1][0], 0, 0, 0);
      C[1][1] = __builtin_amdgcn_mfma_f32_16x16x32_fp8_fp8(a1, b1, C[1][1], 0, 0, 0);
      C[1][2] = __builtin_amdgcn_mfma_f32_16x16x32_fp8_fp8(a1, b2, C[1][2], 0, 0, 0);
      C[1][3] = __builtin_amdgcn_mfma_f32_16x16x32_fp8_fp8(a1, b3, C[1][3], 0, 0, 0);
      C[2][0] = __builtin_amdgcn_mfma_f32_16x16x32_fp8_fp8(a2, b0, C[2][0], 0, 0, 0);
      C[2][1] = __builtin_amdgcn_mfma_f32_16x16x32_fp8_fp8(a2, b1, C[2][1], 0, 0, 0);
      C[2][2] = __builtin_amdgcn_mfma_f32_16x16x32_fp8_fp8(a2, b2, C[2][2], 0, 0, 0);
      C[2][3] = __builtin_amdgcn_mfma_f32_16x16x32_fp8_fp8(a2, b3, C[2][3], 0, 0, 0);
      C[3][0] = __builtin_amdgcn_mfma_f32_16x16x32_fp8_fp8(a3, b0, C[3][0], 0, 0, 0);
      C[3][1] = __builtin_amdgcn_mfma_f32_16x16x32_fp8_fp8(a3, b1, C[3][1], 0, 0, 0);
      C[3][2] = __builtin_amdgcn_mfma_f32_16x16x32_fp8_fp8(a3, b2, C[3][2], 0, 0, 0);
      C[3][3] = __builtin_amdgcn_mfma_f32_16x16x32_fp8_fp8(a3, b3, C[3][3], 0, 0, 0);
    }
    __syncthreads();
  }

  // ---- epilogue (aliases lA/lB; C layout dtype-independent) ----
  float* cmbv = (float*)&lA[0];               // [64][4]
  int*   cmbk = (int*)(cmbv + 256);
  float* bbv  = (float*)(cmbk + 256);
  int*   bbk  = (int*)(bbv + 64);
  int*   lcnt = (int*)(bbk + 64);             // [64]

  #pragma unroll
  for (int mf = 0; mf < 4; ++mf)
    #pragma unroll
    for (int rr = 0; rr < 4; ++rr) {
      float bv = C[mf][0][rr]; int bn = 0;
      #pragma unroll
      for (int nf = 1; nf < 4; ++nf) {
        float v = C[mf][nf][rr];
        if (v > bv) { bv = v; bn = nf; }      // strict >: ties -> lowest nf (lowest k)
      }
      int bk = n0 + wid * 64 + bn * 16 + lc;
      #pragma unroll
      for (int m = 8; m >= 1; m >>= 1) {      // reduce 16 lanes (same quad)
        float vo = __shfl_xor(bv, m); int ko = __shfl_xor(bk, m);
        if (vo > bv || (vo == bv && ko < bk)) { bv = vo; bk = ko; }
      }
      if (lc == 0) {
        int row = mf * 16 + quad * 4 + rr;
        cmbv[row * 4 + wid] = bv; cmbk[row * 4 + wid] = bk;
      }
    }
  __syncthreads();
  if (tid < 64) {
    float bv = cmbv[tid * 4 + 0]; int bk = cmbk[tid * 4 + 0];
    #pragma unroll
    for (int q = 1; q < 4; ++q) {             // ascending wid => ascending k: strict >
      float v = cmbv[tid * 4 + q]; int k = cmbk[tid * 4 + q];
      if (v > bv) { bv = v; bk = k; }
    }
    bbv[tid] = bv; bbk[tid] = bk;
    lcnt[tid] = 0;
    size_t rg = (size_t)(m0 + tid) * NKT + nt;
    pmax[rg] = bv; pidx[rg] = bk;
  }
  __syncthreads();
  // emit near-max extras (cnt records TRUE count; >7 signals finalize full-scan)
  #pragma unroll
  for (int mf = 0; mf < 4; ++mf)
    #pragma unroll
    for (int nf = 0; nf < 4; ++nf)
      #pragma unroll
      for (int rr = 0; rr < 4; ++rr) {
        int row = mf * 16 + quad * 4 + rr;
        float v = C[mf][nf][rr];
        if (v >= bbv[row] - MARGIN_A) {
          int k = n0 + wid * 64 + nf * 16 + lc;
          if (k != bbk[row]) {
            int slot = atomicAdd(&lcnt[row], 1);
            if (slot < 7) extk[((size_t)(m0 + row) * NKT + nt) * 7 + slot] = k;
          }
        }
      }
  __syncthreads();
  if (tid < 64) cnt[(size_t)(m0 + tid) * NKT + nt] = lcnt[tid];
}

// per-row finalize: candidate gather -> block-cooperative LDS staging of candidate
// emb rows (coalesced) -> EXACT bit-identical d-ascending fmaf chains from LDS;
// overflow/full-scan fall back to global chains (rare). Outputs + loss partial.
__global__ __launch_bounds__(256, 2)
void vq_finalize(const float* __restrict__ z, const float* __restrict__ emb,
                 const float* __restrict__ s1g,
                 const float* __restrict__ pmax, const int* __restrict__ pidx,
                 const int* __restrict__ cnt, const int* __restrict__ extk,
                 float* __restrict__ out, double* __restrict__ part) {
  __shared__ float4 lstage4[NSTAGE * 129];   // staged emb rows, stride 129 f4 (2064B)
  __shared__ float4 zst4[4 * 130];           // 4 z rows (broadcast reads)
  __shared__ int candk[4][256];
  __shared__ unsigned char smap[4][256];
  __shared__ unsigned char cw[4][32];
  __shared__ int smeta[NSTAGE];
  __shared__ int scnt;
  __shared__ double lossp[4];

  const int w = threadIdx.x >> 6, l = threadIdx.x & 63;
  const int row = blockIdx.x * 4 + w;
  const int l5 = l & 31;
  const size_t rb = (size_t)row * NKT;
  if (threadIdx.x == 0) scnt = 0;

  // stage this wave's z row (wave-local write/read; exact fp32 bits)
  const float* zr = z + (size_t)row * DIM;
  const float4* zg4 = (const float4*)zr;
  zst4[w * 130 + l * 2]     = zg4[l * 2];
  zst4[w * 130 + l * 2 + 1] = zg4[l * 2 + 1];

  float pv = pmax[rb + l5]; int pk = pidx[rb + l5];
  float gv = pv; int gk = pk;
  #pragma unroll
  for (int m = 16; m >= 1; m >>= 1) {
    float vo = __shfl_xor(gv, m); int ko = __shfl_xor(gk, m);
    if (vo > gv || (vo == gv && ko < gk)) { gv = vo; gk = ko; }
  }
  const bool inm = (l < 32) && (pv >= gv - MARGIN_A);
  int c = 0; bool ovf = false;
  if (inm) { c = cnt[rb + l5]; ovf = (c > 7); }
  unsigned int mask32 = (unsigned int)__ballot(ovf);   // bits 0..31 = ovf tiles
  __syncthreads();                                     // scnt=0 visible

  if (l < 32) {
    unsigned char cc = 0;
    if (inm && !ovf) {
      cc = (unsigned char)(1 + c);
      int si0 = atomicAdd(&scnt, 1 + c);
      // j = 0: tile argmax pk
      candk[w][l5 * 8] = pk;
      smap[w][l5 * 8] = (unsigned char)(si0 < NSTAGE ? si0 : 255);
      if (si0 < NSTAGE) smeta[si0] = pk;
      for (int i = 0; i < c; ++i) {
        int kk = extk[(rb + l5) * 7 + i];
        int slot = l5 * 8 + 1 + i, si = si0 + 1 + i;
        candk[w][slot] = kk;
        smap[w][slot] = (unsigned char)(si < NSTAGE ? si : 255);
        if (si < NSTAGE) smeta[si] = kk;
      }
    }
    cw[w][l5] = cc;
  }
  __syncthreads();
  // cooperative staging: wave w stages rows w, w+4, ... (coalesced 2KB each)
  int sc = scnt; if (sc > NSTAGE) sc = NSTAGE;
  for (int si = w; si < sc; si += 4) {
    const float4* e4 = (const float4*)(emb + (size_t)smeta[si] * DIM);
    lstage4[si * 129 + l * 2]     = e4[l * 2];
    lstage4[si * 129 + l * 2 + 1] = e4[l * 2 + 1];
  }
  __syncthreads();

  float qb = 1e30f; int kb = 0x7fffffff;
  const float s1 = s1g[row];
  const float4* zz4 = &zst4[w * 130];
  for (int g = 0; g < 4; ++g) {
    int ci = g * 64 + l;
    bool act = (ci & 7) < cw[w][ci >> 3];
    int k = 0, si = 255;
    if (act) { k = candk[w][ci]; si = smap[w][ci]; }
    if (act && si != 255) {                    // LDS fast path (bit-exact chain)
      const float4* er4 = &lstage4[si * 129];
      float d = 0.f;
      #pragma unroll
      for (int i4 = 0; i4 < 128; ++i4) {
        float4 ev = er4[i4], zv = zz4[i4];
        d = fmaf(zv.x, ev.x, d); d = fmaf(zv.y, ev.y, d);
        d = fmaf(zv.z, ev.z, d); d = fmaf(zv.w, ev.w, d);
      }
      float q = s1 - 2.f * d;
      if (q < qb || (q == qb && k < kb)) { qb = q; kb = k; }
    }
    if (act && si == 255) {                    // stage overflow: global chain (rare)
      const float4* er4 = (const float4*)(emb + (size_t)k * DIM);
      float d = 0.f;
      for (int i4 = 0; i4 < 128; ++i4) {
        float4 ev = er4[i4], zv = zz4[i4];
        d = fmaf(zv.x, ev.x, d); d = fmaf(zv.y, ev.y, d);
        d = fmaf(zv.z, ev.z, d); d = fmaf(zv.w, ev.w, d);
      }
      float q = s1 - 2.f * d;
      if (q < qb || (q == qb && k < kb)) { qb = q; kb = k; }
    }
  }
  // full-scan fallback for overflowed in-margin tiles (rare)
  while (mask32) {
    int tile = __builtin_ctz(mask32); mask32 &= mask32 - 1;
    int kbase = tile * 256 + l * 4;
    #pragma unroll
    for (int j = 0; j < 4; ++j) {
      int k = kbase + j;
      const float4* er4 = (const float4*)(emb + (size_t)k * DIM);
      float d = 0.f;
      for (int i4 = 0; i4 < 128; ++i4) {
        float4 ev = er4[i4], zv = zz4[i4];
        d = fmaf(zv.x, ev.x, d); d = fmaf(zv.y, ev.y, d);
        d = fmaf(zv.z, ev.z, d); d = fmaf(zv.w, ev.w, d);
      }
      float q = s1 - 2.f * d;
      if (q < qb || (q == qb && k < kb)) { qb = q; kb = k; }
    }
  }
  #pragma unroll
  for (int m = 32; m >= 1; m >>= 1) {
    float qo = __shfl_xor(qb, m); int ko = __shfl_xor(kb, m);
    if (qo < qb || (qo == qb && ko < kb)) { qb = qo; kb = ko; }
  }

  const float4* qr4 = (const float4*)(emb + (size_t)kb * DIM);
  float4 zv0 = zg4[l * 2], zv1 = zg4[l * 2 + 1];
  float4 qv0 = qr4[l * 2], qv1 = qr4[l * 2 + 1];
  float ls = 0.f; float4 ov0, ov1;
  {
    const float* zp=(const float*)&zv0; const float* qp=(const float*)&qv0; float* op=(float*)&ov0;
    #pragma unroll
    for (int e = 0; e < 4; ++e) { float d2 = qp[e]-zp[e]; op[e] = zp[e]+d2; ls += d2*d2; }
  }
  {
    const float* zp=(const float*)&zv1; const float* qp=(const float*)&qv1; float* op=(float*)&ov1;
    #pragma unroll
    for (int e = 0; e < 4; ++e) { float d2 = qp[e]-zp[e]; op[e] = zp[e]+d2; ls += d2*d2; }
  }
  float4* orow = (float4*)(out + (size_t)row * DIM);
  orow[l * 2] = ov0; orow[l * 2 + 1] = ov1;
  #pragma unroll
  for (int m = 32; m >= 1; m >>= 1) ls += __shfl_xor(ls, m);
  if (l == 0) {
    out[(size_t)N_TOK * DIM + 1 + row] = (float)kb;
    lossp[w] = (double)ls;
  }
  __syncthreads();
  if (threadIdx.x == 0)
    part[blockIdx.x] = lossp[0] + lossp[1] + lossp[2] + lossp[3];
}

// reduce 4096 per-block partials -> loss scalar
__global__ void vq_loss(const double* __restrict__ part, float* __restrict__ out) {
  __shared__ double ws[4];
  const int t = threadIdx.x, w = t >> 6, lane = t & 63;
  double s = 0.0;
  #pragma unroll
  for (int i = 0; i < 16; ++i) s += part[t + i * 256];
  #pragma unroll
  for (int m = 32; m >= 1; m >>= 1) s += __shfl_xor(s, m);
  if (lane == 0) ws[w] = s;
  __syncthreads();
  if (t == 0) {
    double tot = ws[0] + ws[1] + ws[2] + ws[3];
    out[(size_t)N_TOK * DIM] =
        (float)(tot * (1.0 + (double)BETA) / ((double)N_TOK * (double)DIM));
  }
}

extern "C" void kernel_launch(void* const* d_in, const int* in_sizes, int n_in,
                              void* d_out, int out_size, void* d_ws, size_t ws_size,
                              hipStream_t stream) {
  const float* z   = (const float*)d_in[0];
  const float* emb = (const float*)d_in[1];
  float* out = (float*)d_out;
  char* ws = (char*)d_ws;
  int*           cnt  = (int*)(ws + WS_CNT);
  float*         pmax = (float*)(ws + WS_PMAX);
  int*           pidx = (int*)(ws + WS_PIDX);
  int*           extk = (int*)(ws + WS_EXTK);
  float*         s1   = (float*)(ws + WS_S1);
  double*        part = (double*)(ws + WS_PART);
  unsigned char* zh8  = (unsigned char*)(ws + WS_ZH);
  unsigned char* eh8  = (unsigned char*)(ws + WS_EH);

  vq_pack<<<N_TOK / 4 + NEMB / 4, 256, 0, stream>>>(z, emb, zh8, eh8, s1);
  vq_mfma<<<dim3(N_TOK / 64, NEMB / 256), 256, 0, stream>>>(zh8, eh8, pmax, pidx, cnt, extk);
  vq_finalize<<<N_TOK / 4, 256, 0, stream>>>(z, emb, s1, pmax, pidx, cnt, extk, out, part);
  vq_loss<<<1, 256, 0, stream>>>(part, out);
}

// Round 15
// 283.946 us; speedup vs baseline: 2.0852x; 1.5052x over previous
//
#include <hip/hip_runtime.h>

// VectorQuantizer: z [16,1024,512] f32, emb [8192,512] f32
// out: [z_q_st (16384*512 f32)][total_loss (1 f32)][idx as f32 (16384)]
//
// fp8-e4m3 MFMA computes approx dot(z, emb*4096) (argmax acc == argmin dist);
// epilogue keeps per-(row,256-tile) max + extras within MARGIN_A of the tile max;
// finalize rechecks candidates with the EXACT fp32 d-ascending fmaf chain +
// q = fl(s1-2*dot) quantization, lowest-index ties. Overflowed tiles (cnt>7 or
// candidate-list overflow) -> full 256-code exact scan (correctness independent
// of candidate statistics).
//
// Round 15: finalize restructured around a block-level COMPACT candidate list
// (R14 ran full chain loops per wave for ~5 active lanes, and margin 3.2 made
// scnt~34 > NSTAGE -> global-chain spill). MARGIN 2.4 (8.9 sigma_pair), dense
// chain pass (lane ci owns candidate ci), NSTAGE=24 staged rows, 3 blocks/CU.

#define N_TOK 16384
#define DIM   512
#define NEMB  8192
#define BETA  0.25f
#define NKT   32
#define MARGIN_A 2.4f        // scaled units (acc = 4096*dot); ~8.9 sigma_pair recall
#define ESCALE 4096.0f
#define NSTAGE 24            // staged candidate rows per finalize block
#define CLIST  96            // compact candidate list capacity

using f32x4 = __attribute__((ext_vector_type(4))) float;

// ---- ws layout (bytes), total ~33.7 MB ----
#define WS_CNT  0
#define WS_PMAX (N_TOK*NKT*4)
#define WS_PIDX (WS_PMAX + N_TOK*NKT*4)
#define WS_EXTK (WS_PIDX + N_TOK*NKT*4)
#define WS_S1   (WS_EXTK + N_TOK*NKT*7*4)
#define WS_PART (WS_S1   + N_TOK*4)
#define WS_ZH   (WS_PART + (N_TOK/4)*8)
#define WS_EH   (WS_ZH   + N_TOK*DIM)

#define GLDS16(g, l) __builtin_amdgcn_global_load_lds( \
    (const __attribute__((address_space(1))) void*)(g), \
    (__attribute__((address_space(3))) void*)(l), 16, 0, 0)

// RNE float -> OCP e4m3fn byte (|f| < 448 assumed; handles subnormals).
__device__ inline unsigned f2e4m3(float f) {
  unsigned u = __builtin_bit_cast(unsigned, f);
  unsigned s = (u >> 24) & 0x80u;
  float a = __builtin_bit_cast(float, u & 0x7fffffffu);
  if (a < 0.015625f) {                         // e4m3 subnormal, unit 2^-9
    unsigned q = (unsigned)rintf(a * 512.0f);  // 0..8 (8 encodes 2^-6 normal)
    return s | q;
  }
  unsigned m = u & 0x7fffffffu;
  m += 0x7ffffu + ((m >> 20) & 1u);            // RNE to 3-bit mantissa
  unsigned e = (m >> 23) - 127u + 7u;
  return s | (e << 3) | ((m >> 20) & 7u);
}

__device__ inline unsigned pack4(float a, float b, float c, float d) {
  return f2e4m3(a) | (f2e4m3(b) << 8) | (f2e4m3(c) << 16) | (f2e4m3(d) << 24);
}

// Fused pack: blocks [0, N_TOK/4) pack z (scale 1) + s1; rest pack emb (scale 4096).
__global__ void vq_pack(const float* __restrict__ z, const float* __restrict__ emb,
                        unsigned char* __restrict__ zh8, unsigned char* __restrict__ eh8,
                        float* __restrict__ s1) {
  const int w = threadIdx.x >> 6, lane = threadIdx.x & 63;
  if (blockIdx.x < N_TOK / 4) {
    const int row = blockIdx.x * 4 + w;
    const float4* r = (const float4*)(z + (size_t)row * DIM);
    float4 v0 = r[lane * 2], v1 = r[lane * 2 + 1];
    // s1: bit-identical to the passing round-2 path
    float p0=v0.x*v0.x, p1=v0.y*v0.y, p2=v0.z*v0.z, p3=v0.w*v0.w;
    float p4=v1.x*v1.x, p5=v1.y*v1.y, p6=v1.z*v1.z, p7=v1.w*v1.w;
    double s = (double)p0+(double)p1+(double)p2+(double)p3
             + (double)p4+(double)p5+(double)p6+(double)p7;
    #pragma unroll
    for (int m = 32; m >= 1; m >>= 1) s += __shfl_xor(s, m);
    if (lane == 0) s1[row] = (float)s;
    uint2 o;
    o.x = pack4(v0.x, v0.y, v0.z, v0.w);
    o.y = pack4(v1.x, v1.y, v1.z, v1.w);
    const int mt = row >> 6, mi = row & 63;        // kc == lane
    *(uint2*)(zh8 + ((((size_t)mt * 64 + lane) * 64) + mi) * 8) = o;
  } else {
    const int row = (blockIdx.x - N_TOK / 4) * 4 + w;
    const float4* r = (const float4*)(emb + (size_t)row * DIM);
    float4 v0 = r[lane * 2], v1 = r[lane * 2 + 1];
    uint2 o;
    o.x = pack4(v0.x*ESCALE, v0.y*ESCALE, v0.z*ESCALE, v0.w*ESCALE);
    o.y = pack4(v1.x*ESCALE, v1.y*ESCALE, v1.z*ESCALE, v1.w*ESCALE);
    const int nt = row >> 8, ni = row & 255;
    *(uint2*)(eh8 + ((((size_t)nt * 64 + lane) * 256) + ni) * 8) = o;
  }
}

// fp8 MFMA GEMM + fused argmax/candidate epilogue. (unchanged from passing R14)
__global__ __launch_bounds__(256, 4)
void vq_mfma(const unsigned char* __restrict__ zh8, const unsigned char* __restrict__ eh8,
             float* __restrict__ pmax, int* __restrict__ pidx,
             int* __restrict__ cnt, int* __restrict__ extk) {
  __shared__ uint2 lA[16 * 64];    // [kc16][mi(64)]  : 8KB
  __shared__ uint2 lB[16 * 256];   // [kc16][ni(256)] : 32KB

  const int mt = blockIdx.x, nt = blockIdx.y;
  const int n0 = nt * 256, m0 = mt * 64;
  const int tid = threadIdx.x;
  const int wid = tid >> 6, lane = tid & 63;        // wid == wn (1m x 4n)
  const int quad = lane >> 4, lc = lane & 15;

  f32x4 C[4][4];
  #pragma unroll
  for (int i = 0; i < 4; ++i)
    #pragma unroll
    for (int j = 0; j < 4; ++j) C[i][j] = (f32x4){0.f, 0.f, 0.f, 0.f};

  const char* gA = (const char*)zh8 + (size_t)mt * 32768;   // 64kc*64mi*8B panel
  const char* gB = (const char*)eh8 + (size_t)nt * 131072;  // 64kc*256ni*8B panel

  for (int t = 0; t < 4; ++t) {                // K-tile of 128 (16 kc-chunks)
    {
      const char* a = gA + (size_t)t * 8192;
      const char* b = gB + (size_t)t * 32768;
      GLDS16(a + tid * 16,        (char*)&lA[0] + tid * 16);
      GLDS16(a + 4096 + tid * 16, (char*)&lA[0] + 4096 + tid * 16);
      #pragma unroll
      for (int i = 0; i < 8; ++i)
        GLDS16(b + i * 4096 + tid * 16, (char*)&lB[0] + i * 4096 + tid * 16);
    }
    __syncthreads();
    #pragma unroll
    for (int s = 0; s < 4; ++s) {              // four K=32 slots per BK=128 tile
      const int kx = s * 4 + quad;
      long long a0 = __builtin_bit_cast(long long, lA[kx * 64 +  0 + lc]);
      long long a1 = __builtin_bit_cast(long long, lA[kx * 64 + 16 + lc]);
      long long a2 = __builtin_bit_cast(long long, lA[kx * 64 + 32 + lc]);
      long long a3 = __builtin_bit_cast(long long, lA[kx * 64 + 48 + lc]);
      long long b0 = __builtin_bit_cast(long long, lB[kx * 256 + wid * 64 +  0 + lc]);
      long long b1 = __builtin_bit_cast(long long, lB[kx * 256 + wid * 64 + 16 + lc]);
      long long b2 = __builtin_bit_cast(long long, lB[kx * 256 + wid * 64 + 32 + lc]);
      long long b3 = __builtin_bit_cast(long long, lB[kx * 256 + wid * 64 + 48 + lc]);
      C[0][0] = __builtin_amdgcn_mfma_f32_16x16x32_fp8_fp8(a0, b0, C[0][0], 0, 0, 0);
      C[0][1] = __builtin_amdgcn_mfma_f32_16x16x32_fp8_fp8(a0, b1, C[0][1], 0, 0, 0);
      C[0][2] = __builtin_amdgcn_mfma_f32_16x16x32_fp8_fp8(a0, b2, C[0][2], 0, 0, 0);
      C[0][3] = __builtin_amdgcn_mfma_f32_16x16x32_fp8_fp8(a0, b3, C[0][3], 0, 0, 0);
      C[1][0] = __builtin_amdgcn_mfma_f32_16x16x32_fp8_fp8(a1, b0, C[1][0], 0, 0, 0);
      C[1][1] = __builtin_amdgcn_mfma_f32_16x16x32_fp8_fp8(a1, b1, C[1][1], 0, 0, 0);
      C[1][2] = __builtin_amdgcn_mfma_f32_16x16x32_fp8_fp8(a1, b2, C[1][2], 0, 0, 0);
      C[1][3] = __builtin_amdgcn_mfma_f32_16x16x32_fp8_fp8(a1, b3, C[1][3], 0, 0, 0);
      C[2][0] = __builtin_amdgcn_mfma_f32_16x16x32_fp8_fp8(a2, b0, C[2][0], 0, 0, 0);
      C[2][1] = __builtin_amdgcn_mfma_f32_16x16x32_fp8_fp8(a2, b1, C[2][1], 0, 0, 0);
      C[2][2] = __builtin_amdgcn_mfma_f32_16x16x32_fp8_fp8(a2, b2, C[2][2], 0, 0, 0);
      C[2][3] = __builtin_amdgcn_mfma_f32_16x16x32_fp8_fp8(a2, b3, C[2][3], 0, 0, 0);
      C[3][0] = __builtin_amdgcn_mfma_f32_16x16x32_fp8_fp8(a3, b0, C[3][0], 0, 0, 0);
      C[3][1] = __builtin_amdgcn_mfma_f32_16x16x32_fp8_fp8(a3, b1, C[3][1], 0, 0, 0);
      C[3][2] = __builtin_amdgcn_mfma_f32_16x16x32_fp8_fp8(a3, b2, C[3][2], 0, 0, 0);
      C[3][3] = __builtin_amdgcn_mfma_f32_16x16x32_fp8_fp8(a3, b3, C[3][3], 0, 0, 0);
    }
    __syncthreads();
  }

  // ---- epilogue (aliases lA/lB; C layout dtype-independent) ----
  float* cmbv = (float*)&lA[0];               // [64][4]
  int*   cmbk = (int*)(cmbv + 256);
  float* bbv  = (float*)(cmbk + 256);
  int*   bbk  = (int*)(bbv + 64);
  int*   lcnt = (int*)(bbk + 64);             // [64]

  #pragma unroll
  for (int mf = 0; mf < 4; ++mf)
    #pragma unroll
    for (int rr = 0; rr < 4; ++rr) {
      float bv = C[mf][0][rr]; int bn = 0;
      #pragma unroll
      for (int nf = 1; nf < 4; ++nf) {
        float v = C[mf][nf][rr];
        if (v > bv) { bv = v; bn = nf; }      // strict >: ties -> lowest nf (lowest k)
      }
      int bk = n0 + wid * 64 + bn * 16 + lc;
      #pragma unroll
      for (int m = 8; m >= 1; m >>= 1) {      // reduce 16 lanes (same quad)
        float vo = __shfl_xor(bv, m); int ko = __shfl_xor(bk, m);
        if (vo > bv || (vo == bv && ko < bk)) { bv = vo; bk = ko; }
      }
      if (lc == 0) {
        int row = mf * 16 + quad * 4 + rr;
        cmbv[row * 4 + wid] = bv; cmbk[row * 4 + wid] = bk;
      }
    }
  __syncthreads();
  if (tid < 64) {
    float bv = cmbv[tid * 4 + 0]; int bk = cmbk[tid * 4 + 0];
    #pragma unroll
    for (int q = 1; q < 4; ++q) {             // ascending wid => ascending k: strict >
      float v = cmbv[tid * 4 + q]; int k = cmbk[tid * 4 + q];
      if (v > bv) { bv = v; bk = k; }
    }
    bbv[tid] = bv; bbk[tid] = bk;
    lcnt[tid] = 0;
    size_t rg = (size_t)(m0 + tid) * NKT + nt;
    pmax[rg] = bv; pidx[rg] = bk;
  }
  __syncthreads();
  // emit near-max extras (cnt records TRUE count; >7 signals finalize full-scan)
  #pragma unroll
  for (int mf = 0; mf < 4; ++mf)
    #pragma unroll
    for (int nf = 0; nf < 4; ++nf)
      #pragma unroll
      for (int rr = 0; rr < 4; ++rr) {
        int row = mf * 16 + quad * 4 + rr;
        float v = C[mf][nf][rr];
        if (v >= bbv[row] - MARGIN_A) {
          int k = n0 + wid * 64 + nf * 16 + lc;
          if (k != bbk[row]) {
            int slot = atomicAdd(&lcnt[row], 1);
            if (slot < 7) extk[((size_t)(m0 + row) * NKT + nt) * 7 + slot] = k;
          }
        }
      }
  __syncthreads();
  if (tid < 64) cnt[(size_t)(m0 + tid) * NKT + nt] = lcnt[tid];
}

// per-row finalize: compact block-level candidate list -> cooperative LDS staging
// (coalesced) -> DENSE chain pass (lane ci owns candidate ci; exact f4 x,y,z,w
// d-ascending fmaf chain) -> per-row selection scan; cnt>7 / list-overflow tiles
// get a full 256-code exact scan. Outputs + per-block loss partial.
__global__ __launch_bounds__(256, 3)
void vq_finalize(const float* __restrict__ z, const float* __restrict__ emb,
                 const float* __restrict__ s1g,
                 const float* __restrict__ pmax, const int* __restrict__ pidx,
                 const int* __restrict__ cnt, const int* __restrict__ extk,
                 float* __restrict__ out, double* __restrict__ part) {
  __shared__ float4 lstage4[NSTAGE * 129];   // staged emb rows (stride 129 f4)
  __shared__ int   ck[CLIST];
  __shared__ float cq[CLIST];
  __shared__ unsigned char cmeta[CLIST];     // row-in-block (0..3)
  __shared__ int ccnt;
  __shared__ double lossp[4];

  const int w = threadIdx.x >> 6, l = threadIdx.x & 63;
  const int row = blockIdx.x * 4 + w;
  const int l5 = l & 31;
  const size_t rb = (size_t)row * NKT;
  if (threadIdx.x == 0) ccnt = 0;

  float pv = pmax[rb + l5]; int pk = pidx[rb + l5];
  float gv = pv; int gk = pk;
  #pragma unroll
  for (int m = 16; m >= 1; m >>= 1) {
    float vo = __shfl_xor(gv, m); int ko = __shfl_xor(gk, m);
    if (vo > gv || (vo == gv && ko < gk)) { gv = vo; gk = ko; }
  }
  const bool inm = (l < 32) && (pv >= gv - MARGIN_A);
  int c = 0; bool ovf = false;
  if (inm) { c = cnt[rb + l5]; if (c > 7) { ovf = true; c = 0; } }
  __syncthreads();                           // ccnt=0 visible before atomics

  bool ovf2 = false;
  if (inm && !ovf) {
    int base = atomicAdd(&ccnt, 1 + c);
    if (base < CLIST) { ck[base] = pk; cmeta[base] = (unsigned char)w; }
    else ovf2 = true;
    for (int i = 0; i < c; ++i) {
      int idx = base + 1 + i;
      if (idx < CLIST) { ck[idx] = extk[(rb + l5) * 7 + i]; cmeta[idx] = (unsigned char)w; }
      else ovf2 = true;
    }
  }
  // per-wave (= per-row) full-scan mask; lanes 32-63 have inm=false
  unsigned int mask32 = (unsigned int)__ballot(ovf || ovf2);
  __syncthreads();
  int cN = ccnt; if (cN > CLIST) cN = CLIST;
  int sN = cN;   if (sN > NSTAGE) sN = NSTAGE;

  // cooperative staging: wave w stages rows w, w+4, ... (coalesced 2KB each)
  for (int si = w; si < sN; si += 4) {
    const float4* e4 = (const float4*)(emb + (size_t)ck[si] * DIM);
    lstage4[si * 129 + l * 2]     = e4[l * 2];
    lstage4[si * 129 + l * 2 + 1] = e4[l * 2 + 1];
  }
  __syncthreads();

  // dense chain pass: thread ci owns candidate ci (exact f4 d-ascending chain)
  for (int ci = threadIdx.x; ci < cN; ci += 256) {
    const int k = ck[ci];
    const int r = cmeta[ci];
    const float4* zr4 = (const float4*)(z + (size_t)(blockIdx.x * 4 + r) * DIM);
    float d = 0.f;
    if (ci < NSTAGE) {
      const float4* er4 = &lstage4[ci * 129];
      for (int i4 = 0; i4 < 128; ++i4) {
        float4 zv = zr4[i4], ev = er4[i4];
        d = fmaf(zv.x, ev.x, d); d = fmaf(zv.y, ev.y, d);
        d = fmaf(zv.z, ev.z, d); d = fmaf(zv.w, ev.w, d);
      }
    } else {                                  // list beyond staged (rare)
      const float4* er4 = (const float4*)(emb + (size_t)k * DIM);
      for (int i4 = 0; i4 < 128; ++i4) {
        float4 zv = zr4[i4], ev = er4[i4];
        d = fmaf(zv.x, ev.x, d); d = fmaf(zv.y, ev.y, d);
        d = fmaf(zv.z, ev.z, d); d = fmaf(zv.w, ev.w, d);
      }
    }
    cq[ci] = s1g[blockIdx.x * 4 + r] - 2.f * d;   // single-rounding quantize
  }

  // full-scan fallback for this row's overflowed tiles (rare)
  float qb = 1e30f; int kb = 0x7fffffff;
  const float s1 = s1g[row];
  const float4* zw4 = (const float4*)(z + (size_t)row * DIM);
  while (mask32) {
    int tile = __builtin_ctz(mask32); mask32 &= mask32 - 1;
    int kbase = tile * 256 + l * 4;
    #pragma unroll
    for (int j = 0; j < 4; ++j) {
      int k = kbase + j;
      const float4* er4 = (const float4*)(emb + (size_t)k * DIM);
      float d = 0.f;
      for (int i4 = 0; i4 < 128; ++i4) {
        float4 zv = zw4[i4], ev = er4[i4];
        d = fmaf(zv.x, ev.x, d); d = fmaf(zv.y, ev.y, d);
        d = fmaf(zv.z, ev.z, d); d = fmaf(zv.w, ev.w, d);
      }
      float q = s1 - 2.f * d;
      if (q < qb || (q == qb && k < kb)) { qb = q; kb = k; }
    }
  }
  __syncthreads();                            // cq ready

  // per-row selection scan over the compact list
  for (int e = l; e < cN; e += 64) {
    if (cmeta[e] == (unsigned char)w) {
      float q = cq[e]; int k = ck[e];
      if (q < qb || (q == qb && k < kb)) { qb = q; kb = k; }
    }
  }
  #pragma unroll
  for (int m = 32; m >= 1; m >>= 1) {
    float qo = __shfl_xor(qb, m); int ko = __shfl_xor(kb, m);
    if (qo < qb || (qo == qb && ko < kb)) { qb = qo; kb = ko; }
  }

  const float4* qr4 = (const float4*)(emb + (size_t)kb * DIM);
  float4 zv0 = zw4[l * 2], zv1 = zw4[l * 2 + 1];
  float4 qv0 = qr4[l * 2], qv1 = qr4[l * 2 + 1];
  float ls = 0.f; float4 ov0, ov1;
  {
    const float* zp=(const float*)&zv0; const float* qp=(const float*)&qv0; float* op=(float*)&ov0;
    #pragma unroll
    for (int e = 0; e < 4; ++e) { float d2 = qp[e]-zp[e]; op[e] = zp[e]+d2; ls += d2*d2; }
  }
  {
    const float* zp=(const float*)&zv1; const float* qp=(const float*)&qv1; float* op=(float*)&ov1;
    #pragma unroll
    for (int e = 0; e < 4; ++e) { float d2 = qp[e]-zp[e]; op[e] = zp[e]+d2; ls += d2*d2; }
  }
  float4* orow = (float4*)(out + (size_t)row * DIM);
  orow[l * 2] = ov0; orow[l * 2 + 1] = ov1;
  #pragma unroll
  for (int m = 32; m >= 1; m >>= 1) ls += __shfl_xor(ls, m);
  if (l == 0) {
    out[(size_t)N_TOK * DIM + 1 + row] = (float)kb;
    lossp[w] = (double)ls;
  }
  __syncthreads();
  if (threadIdx.x == 0)
    part[blockIdx.x] = lossp[0] + lossp[1] + lossp[2] + lossp[3];
}

// reduce 4096 per-block partials -> loss scalar
__global__ void vq_loss(const double* __restrict__ part, float* __restrict__ out) {
  __shared__ double ws[4];
  const int t = threadIdx.x, w = t >> 6, lane = t & 63;
  double s = 0.0;
  #pragma unroll
  for (int i = 0; i < 16; ++i) s += part[t + i * 256];
  #pragma unroll
  for (int m = 32; m >= 1; m >>= 1) s += __shfl_xor(s, m);
  if (lane == 0) ws[w] = s;
  __syncthreads();
  if (t == 0) {
    double tot = ws[0] + ws[1] + ws[2] + ws[3];
    out[(size_t)N_TOK * DIM] =
        (float)(tot * (1.0 + (double)BETA) / ((double)N_TOK * (double)DIM));
  }
}

extern "C" void kernel_launch(void* const* d_in, const int* in_sizes, int n_in,
                              void* d_out, int out_size, void* d_ws, size_t ws_size,
                              hipStream_t stream) {
  const float* z   = (const float*)d_in[0];
  const float* emb = (const float*)d_in[1];
  float* out = (float*)d_out;
  char* ws = (char*)d_ws;
  int*           cnt  = (int*)(ws + WS_CNT);
  float*         pmax = (float*)(ws + WS_PMAX);
  int*           pidx = (int*)(ws + WS_PIDX);
  int*           extk = (int*)(ws + WS_EXTK);
  float*         s1   = (float*)(ws + WS_S1);
  double*        part = (double*)(ws + WS_PART);
  unsigned char* zh8  = (unsigned char*)(ws + WS_ZH);
  unsigned char* eh8  = (unsigned char*)(ws + WS_EH);

  vq_pack<<<N_TOK / 4 + NEMB / 4, 256, 0, stream>>>(z, emb, zh8, eh8, s1);
  vq_mfma<<<dim3(N_TOK / 64, NEMB / 256), 256, 0, stream>>>(zh8, eh8, pmax, pidx, cnt, extk);
  vq_finalize<<<N_TOK / 4, 256, 0, stream>>>(z, emb, s1, pmax, pidx, cnt, extk, out, part);
  vq_loss<<<1, 256, 0, stream>>>(part, out);
}